// Round 16
// baseline (94.212 us; speedup 1.0000x reference)
//
#include <hip/hip_runtime.h>

typedef short bf16x8 __attribute__((ext_vector_type(8)));
typedef float f32x4 __attribute__((ext_vector_type(4)));

__device__ __forceinline__ unsigned short f2bf(float f) {
  union { float f; unsigned int u; } v; v.f = f;
  unsigned int r = v.u + 0x7FFFu + ((v.u >> 16) & 1u);
  return (unsigned short)(r >> 16);
}

__device__ __forceinline__ ushort4 cast4(float4 x) {
  ushort4 o; o.x = f2bf(x.x); o.y = f2bf(x.y); o.z = f2bf(x.z); o.w = f2bf(x.w);
  return o;
}

// ---- fp32->bf16 casts for hs + Wq|Wk|Wv only (Wo is cast inside attn) ----
__global__ __launch_bounds__(256) void prep(
    const float* __restrict__ hs, const float* __restrict__ Wq,
    const float* __restrict__ Wk, const float* __restrict__ Wv,
    unsigned short* __restrict__ hsb, unsigned short* __restrict__ Wqkvb) {
  int b = blockIdx.x;
  const float* src; unsigned short* dst; int base;
  if (b < 384)       { src = hs; dst = hsb;            base = b * 1024; }
  else if (b < 528)  { src = Wq; dst = Wqkvb;          base = (b - 384) * 1024; }
  else if (b < 672)  { src = Wk; dst = Wqkvb + 147456; base = (b - 528) * 1024; }
  else               { src = Wv; dst = Wqkvb + 294912; base = (b - 672) * 1024; }
  int i = base + threadIdx.x * 4;
  *(ushort4*)&dst[i] = cast4(*(const float4*)&src[i]);
}

// ---- QKV GEMM: 32(M)x32(N) tile, split-K x4 (4 MFMA / 4 loads per k-iter).
// Q,K -> QKb[512][384]; V -> Vt[768][512] (transposed).
__global__ __launch_bounds__(256) void gemm_qkv(
    const unsigned short* __restrict__ A, const unsigned short* __restrict__ B,
    unsigned short* __restrict__ QKb, unsigned short* __restrict__ Vt) {
  __shared__ f32x4 part[4][4][64];  // [kpart][subtile][lane]
  const int tid = threadIdx.x;
  const int w = tid >> 6, lane = tid & 63;
  const int lm = lane & 15, quad = lane >> 4;
  const int mt = blockIdx.y * 32;
  const int n0 = blockIdx.x * 32;
  const int kw = w * 192;
  const unsigned short* a_ptr = A + (mt + lm) * 768 + kw + quad * 8;
  const unsigned short* b_ptr = B + (n0 + lm) * 768 + kw + quad * 8;
  f32x4 acc[4] = {{0.f,0.f,0.f,0.f},{0.f,0.f,0.f,0.f},{0.f,0.f,0.f,0.f},{0.f,0.f,0.f,0.f}};
#pragma unroll
  for (int kb = 0; kb < 192; kb += 32) {
    bf16x8 a0 = *(const bf16x8*)(a_ptr + kb);
    bf16x8 a1 = *(const bf16x8*)(a_ptr + 16 * 768 + kb);
    bf16x8 b0 = *(const bf16x8*)(b_ptr + kb);
    bf16x8 b1 = *(const bf16x8*)(b_ptr + 16 * 768 + kb);
    acc[0] = __builtin_amdgcn_mfma_f32_16x16x32_bf16(a0, b0, acc[0], 0, 0, 0);
    acc[1] = __builtin_amdgcn_mfma_f32_16x16x32_bf16(a0, b1, acc[1], 0, 0, 0);
    acc[2] = __builtin_amdgcn_mfma_f32_16x16x32_bf16(a1, b0, acc[2], 0, 0, 0);
    acc[3] = __builtin_amdgcn_mfma_f32_16x16x32_bf16(a1, b1, acc[3], 0, 0, 0);
  }
#pragma unroll
  for (int s = 0; s < 4; ++s) part[w][s][lane] = acc[s];
  __syncthreads();
  {
    const int m = mt + (w >> 1) * 16;
    const int n = n0 + (w & 1) * 16;
    f32x4 s = part[0][w][lane] + part[1][w][lane] + part[2][w][lane] + part[3][w][lane];
    if (n < 384) {
#pragma unroll
      for (int r = 0; r < 4; ++r)
        QKb[(m + quad * 4 + r) * 384 + n + lm] = f2bf(s[r]);
    } else {
      ushort4 o;
      o.x = f2bf(s[0]); o.y = f2bf(s[1]); o.z = f2bf(s[2]); o.w = f2bf(s[3]);
      *(ushort4*)&Vt[(n - 384 + lm) * 512 + m + quad * 4] = o;
    }
  }
}

// ---- causal taylor attention, atomic-free, fused divide.
// Prologue: grid-strided Wo fp32->bf16 cast (independent work, hides in bubbles).
// Grid (c=8, h=12, tq=4): block owns 16 t-rows; wave w handles sb = w, w+4,.. <= c.
__global__ __launch_bounds__(256) void attn(
    const unsigned short* __restrict__ QKb, const unsigned short* __restrict__ Vt,
    const float* __restrict__ Wo, unsigned short* __restrict__ Wob,
    unsigned short* __restrict__ Yb) {
  const int c = blockIdx.x, h = blockIdx.y, tq = blockIdx.z;
  const int tid = threadIdx.x;
  const int w = tid >> 6, lane = tid & 63;
  const int lm = lane & 15, quad = lane >> 4;
  const int t0 = c * 64, tbase = t0 + tq * 16;
  // Wo cast slice: 384 blocks x 384 ushort4 = 147456 (= 768*768/4)
  {
    const int bid = blockIdx.x + 8 * blockIdx.y + 96 * blockIdx.z;
    const int base = bid * 384;
    for (int i = base + tid; i < base + 384; i += 256)
      ((ushort4*)Wob)[i] = cast4(((const float4*)Wo)[i]);
  }
  __shared__ __align__(16) unsigned short scl[4][16 * 72];  // per-wave scores
  __shared__ __align__(16) f32x4 partAV[4][4][64];          // [wave][dt][lane]
  __shared__ float denb[4][16];
  bf16x8 aq = {0, 0, 0, 0, 0, 0, 0, 0};
  if (quad < 2)
    aq = *(const bf16x8*)&QKb[(tbase + lm) * 384 + h * 16 + quad * 8];
  f32x4 av[4] = {{0.f,0.f,0.f,0.f},{0.f,0.f,0.f,0.f},{0.f,0.f,0.f,0.f},{0.f,0.f,0.f,0.f}};
  float dsum[4] = {0.f, 0.f, 0.f, 0.f};
  const unsigned short* vbase = Vt + (h * 64 + lm) * 512;
  unsigned short* sw = &scl[w][0];
  for (int sb = w; sb <= c; sb += 4) {
    const int s0 = sb * 64;
    f32x4 qk[4];
#pragma unroll
    for (int sbt = 0; sbt < 4; ++sbt) {
      bf16x8 bk = {0, 0, 0, 0, 0, 0, 0, 0};
      if (quad < 2)
        bk = *(const bf16x8*)&QKb[(s0 + sbt * 16 + lm) * 384 + 192 + h * 16 + quad * 8];
      f32x4 z = {0.f, 0.f, 0.f, 0.f};
      qk[sbt] = __builtin_amdgcn_mfma_f32_16x16x32_bf16(aq, bk, z, 0, 0, 0);
    }
#pragma unroll
    for (int sbt = 0; sbt < 4; ++sbt) {
#pragma unroll
      for (int r = 0; r < 4; ++r) {
        const int tl = tbase + quad * 4 + r;       // global t
        const int sl = sbt * 16 + lm;              // s within tile
        float x = qk[sbt][r];
        float val = (s0 + sl <= tl) ? 1.f + 0.25f * x + 0.03125f * x * x : 0.f;
        dsum[r] += val;
        sw[(quad * 4 + r) * 72 + sl] = f2bf(val);
      }
    }
#pragma unroll
    for (int kb = 0; kb < 2; ++kb) {
      bf16x8 a = *(const bf16x8*)&sw[lm * 72 + kb * 32 + quad * 8];
#pragma unroll
      for (int dt = 0; dt < 4; ++dt) {
        bf16x8 b = *(const bf16x8*)&vbase[dt * 16 * 512 + s0 + kb * 32 + quad * 8];
        av[dt] = __builtin_amdgcn_mfma_f32_16x16x32_bf16(a, b, av[dt], 0, 0, 0);
      }
    }
  }
#pragma unroll
  for (int r = 0; r < 4; ++r) {
    float v = dsum[r];
    v += __shfl_xor(v, 1); v += __shfl_xor(v, 2);
    v += __shfl_xor(v, 4); v += __shfl_xor(v, 8);
    if (lm == 0) denb[w][quad * 4 + r] = v;
  }
#pragma unroll
  for (int dt = 0; dt < 4; ++dt) partAV[w][dt][lane] = av[dt];
  __syncthreads();
  {
    // wave w finalizes d-tile dt=w: y = num/den, bf16
    f32x4 s = partAV[0][w][lane] + partAV[1][w][lane] +
              partAV[2][w][lane] + partAV[3][w][lane];
#pragma unroll
    for (int r = 0; r < 4; ++r) {
      const int row = quad * 4 + r;
      float den = denb[0][row] + denb[1][row] + denb[2][row] + denb[3][row] + 1e-12f;
      Yb[(tbase + row) * 768 + h * 64 + w * 16 + lm] = f2bf(s[r] / den);
    }
  }
}

// ---- out GEMM: pure bf16 32x32 tile, split-K x4: out = Yb @ Wo^T ----
__global__ __launch_bounds__(256) void gemm_out(
    const unsigned short* __restrict__ Yb, const unsigned short* __restrict__ Wob,
    float* __restrict__ out) {
  __shared__ f32x4 part[4][4][64];
  const int tid = threadIdx.x;
  const int w = tid >> 6, lane = tid & 63;
  const int lm = lane & 15, quad = lane >> 4;
  const int mt = blockIdx.y * 32;
  const int n0 = blockIdx.x * 32;
  const int kw = w * 192;
  const unsigned short* a_ptr = Yb + (mt + lm) * 768 + kw + quad * 8;
  const unsigned short* b_ptr = Wob + (n0 + lm) * 768 + kw + quad * 8;
  f32x4 acc[4] = {{0.f,0.f,0.f,0.f},{0.f,0.f,0.f,0.f},{0.f,0.f,0.f,0.f},{0.f,0.f,0.f,0.f}};
#pragma unroll
  for (int kb = 0; kb < 192; kb += 32) {
    bf16x8 a0 = *(const bf16x8*)(a_ptr + kb);
    bf16x8 a1 = *(const bf16x8*)(a_ptr + 16 * 768 + kb);
    bf16x8 b0 = *(const bf16x8*)(b_ptr + kb);
    bf16x8 b1 = *(const bf16x8*)(b_ptr + 16 * 768 + kb);
    acc[0] = __builtin_amdgcn_mfma_f32_16x16x32_bf16(a0, b0, acc[0], 0, 0, 0);
    acc[1] = __builtin_amdgcn_mfma_f32_16x16x32_bf16(a0, b1, acc[1], 0, 0, 0);
    acc[2] = __builtin_amdgcn_mfma_f32_16x16x32_bf16(a1, b0, acc[2], 0, 0, 0);
    acc[3] = __builtin_amdgcn_mfma_f32_16x16x32_bf16(a1, b1, acc[3], 0, 0, 0);
  }
#pragma unroll
  for (int s = 0; s < 4; ++s) part[w][s][lane] = acc[s];
  __syncthreads();
  {
    const int m = mt + (w >> 1) * 16;
    const int n = n0 + (w & 1) * 16;
    f32x4 s = part[0][w][lane] + part[1][w][lane] + part[2][w][lane] + part[3][w][lane];
#pragma unroll
    for (int r = 0; r < 4; ++r)
      out[(m + quad * 4 + r) * 768 + n + lm] = s[r];
  }
}

extern "C" void kernel_launch(void* const* d_in, const int* in_sizes, int n_in,
                              void* d_out, int out_size, void* d_ws, size_t ws_size,
                              hipStream_t stream) {
  const float* hs = (const float*)d_in[0];
  const float* Wq = (const float*)d_in[1];
  const float* Wk = (const float*)d_in[2];
  const float* Wv = (const float*)d_in[3];
  const float* Wo = (const float*)d_in[4];
  float* out = (float*)d_out;
  float* ws = (float*)d_ws;

  unsigned short* Yb    = (unsigned short*)ws;             // 393216 us
  unsigned short* hsb   = Yb + 393216;                     // 393216 us
  unsigned short* Wqkvb = hsb + 393216;                    // 884736 us
  unsigned short* Wob   = Wqkvb + 884736;                  // 589824 us
  unsigned short* QKb   = Wob + 589824;                    // 196608 us
  unsigned short* Vt    = QKb + 196608;                    // 393216 us

  // casts for hs + Wqkv (critical path to gemm_qkv; Wo deferred to attn)
  prep<<<dim3(1248), 256, 0, stream>>>(hs, Wq, Wk, Wv, hsb, Wqkvb);
  // QKV projections; V emitted transposed (32x32 tiles)
  gemm_qkv<<<dim3(36, 16), 256, 0, stream>>>(hsb, Wqkvb, QKb, Vt);
  // causal taylor attention -> Yb = bf16(num/den); also casts Wo -> Wob
  attn<<<dim3(8, 12, 4), 256, 0, stream>>>(QKb, Vt, Wo, Wob, Yb);
  // out = Yb @ Wo^T (pure bf16 GEMM)
  gemm_out<<<dim3(24, 16), 256, 0, stream>>>(Yb, Wob, out);
}

// Round 17
// 92.248 us; speedup vs baseline: 1.0213x; 1.0213x over previous
//
#include <hip/hip_runtime.h>

typedef short bf16x8 __attribute__((ext_vector_type(8)));
typedef float f32x4 __attribute__((ext_vector_type(4)));

__device__ __forceinline__ unsigned short f2bf(float f) {
  union { float f; unsigned int u; } v; v.f = f;
  unsigned int r = v.u + 0x7FFFu + ((v.u >> 16) & 1u);
  return (unsigned short)(r >> 16);
}

__device__ __forceinline__ ushort4 cast4(float4 x) {
  ushort4 o; o.x = f2bf(x.x); o.y = f2bf(x.y); o.z = f2bf(x.z); o.w = f2bf(x.w);
  return o;
}

// ---- one-pass fp32->bf16 casts, 8 elems/thread (16B stores), 912 blocks ----
__global__ __launch_bounds__(256) void prep(
    const float* __restrict__ hs, const float* __restrict__ Wq,
    const float* __restrict__ Wk, const float* __restrict__ Wv,
    const float* __restrict__ Wo, unsigned short* __restrict__ hsb,
    unsigned short* __restrict__ Wqkvb, unsigned short* __restrict__ Wob) {
  int b = blockIdx.x;
  const float* src; unsigned short* dst; int base;
  if (b < 192)      { src = hs; dst = hsb;            base = b * 2048; }
  else if (b < 264) { src = Wq; dst = Wqkvb;          base = (b - 192) * 2048; }
  else if (b < 336) { src = Wk; dst = Wqkvb + 147456; base = (b - 264) * 2048; }
  else if (b < 624) { src = Wv; dst = Wqkvb + 294912; base = (b - 336) * 2048; }
  else              { src = Wo; dst = Wob;            base = (b - 624) * 2048; }
  int i = base + threadIdx.x * 8;
  ushort4 o0 = cast4(*(const float4*)&src[i]);
  ushort4 o1 = cast4(*(const float4*)&src[i + 4]);
  *(ushort4*)&dst[i] = o0;
  *(ushort4*)&dst[i + 4] = o1;
}

// ---- QKV GEMM: 32(M)x32(N) tile, split-K x4 (4 MFMA / 4 loads per k-iter).
// Q,K -> QKb[512][384]; V -> Vt[768][512] (transposed).
__global__ __launch_bounds__(256) void gemm_qkv(
    const unsigned short* __restrict__ A, const unsigned short* __restrict__ B,
    unsigned short* __restrict__ QKb, unsigned short* __restrict__ Vt) {
  __shared__ f32x4 part[4][4][64];  // [kpart][subtile][lane]
  const int tid = threadIdx.x;
  const int w = tid >> 6, lane = tid & 63;
  const int lm = lane & 15, quad = lane >> 4;
  const int mt = blockIdx.y * 32;
  const int n0 = blockIdx.x * 32;
  const int kw = w * 192;
  const unsigned short* a_ptr = A + (mt + lm) * 768 + kw + quad * 8;
  const unsigned short* b_ptr = B + (n0 + lm) * 768 + kw + quad * 8;
  f32x4 acc[4] = {{0.f,0.f,0.f,0.f},{0.f,0.f,0.f,0.f},{0.f,0.f,0.f,0.f},{0.f,0.f,0.f,0.f}};
#pragma unroll
  for (int kb = 0; kb < 192; kb += 32) {
    bf16x8 a0 = *(const bf16x8*)(a_ptr + kb);
    bf16x8 a1 = *(const bf16x8*)(a_ptr + 16 * 768 + kb);
    bf16x8 b0 = *(const bf16x8*)(b_ptr + kb);
    bf16x8 b1 = *(const bf16x8*)(b_ptr + 16 * 768 + kb);
    acc[0] = __builtin_amdgcn_mfma_f32_16x16x32_bf16(a0, b0, acc[0], 0, 0, 0);
    acc[1] = __builtin_amdgcn_mfma_f32_16x16x32_bf16(a0, b1, acc[1], 0, 0, 0);
    acc[2] = __builtin_amdgcn_mfma_f32_16x16x32_bf16(a1, b0, acc[2], 0, 0, 0);
    acc[3] = __builtin_amdgcn_mfma_f32_16x16x32_bf16(a1, b1, acc[3], 0, 0, 0);
  }
#pragma unroll
  for (int s = 0; s < 4; ++s) part[w][s][lane] = acc[s];
  __syncthreads();
  {
    const int m = mt + (w >> 1) * 16;
    const int n = n0 + (w & 1) * 16;
    f32x4 s = part[0][w][lane] + part[1][w][lane] + part[2][w][lane] + part[3][w][lane];
    if (n < 384) {
#pragma unroll
      for (int r = 0; r < 4; ++r)
        QKb[(m + quad * 4 + r) * 384 + n + lm] = f2bf(s[r]);
    } else {
      ushort4 o;
      o.x = f2bf(s[0]); o.y = f2bf(s[1]); o.z = f2bf(s[2]); o.w = f2bf(s[3]);
      *(ushort4*)&Vt[(n - 384 + lm) * 512 + m + quad * 4] = o;
    }
  }
}

// ---- causal taylor attention, atomic-free, fused divide.
// Grid (c=8, h=12, tq=4): block owns 16 t-rows; wave w handles sb = w, w+4,.. <= c,
// accumulating AV in registers; LDS reduction; emits Yb = bf16(num/den) directly.
__global__ __launch_bounds__(256) void attn(
    const unsigned short* __restrict__ QKb, const unsigned short* __restrict__ Vt,
    unsigned short* __restrict__ Yb) {
  const int c = blockIdx.x, h = blockIdx.y, tq = blockIdx.z;
  const int tid = threadIdx.x;
  const int w = tid >> 6, lane = tid & 63;
  const int lm = lane & 15, quad = lane >> 4;
  const int t0 = c * 64, tbase = t0 + tq * 16;
  __shared__ __align__(16) unsigned short scl[4][16 * 72];  // per-wave scores
  __shared__ __align__(16) f32x4 partAV[4][4][64];          // [wave][dt][lane]
  __shared__ float denb[4][16];
  bf16x8 aq = {0, 0, 0, 0, 0, 0, 0, 0};
  if (quad < 2)
    aq = *(const bf16x8*)&QKb[(tbase + lm) * 384 + h * 16 + quad * 8];
  f32x4 av[4] = {{0.f,0.f,0.f,0.f},{0.f,0.f,0.f,0.f},{0.f,0.f,0.f,0.f},{0.f,0.f,0.f,0.f}};
  float dsum[4] = {0.f, 0.f, 0.f, 0.f};
  const unsigned short* vbase = Vt + (h * 64 + lm) * 512;
  unsigned short* sw = &scl[w][0];
  for (int sb = w; sb <= c; sb += 4) {
    const int s0 = sb * 64;
    f32x4 qk[4];
#pragma unroll
    for (int sbt = 0; sbt < 4; ++sbt) {
      bf16x8 bk = {0, 0, 0, 0, 0, 0, 0, 0};
      if (quad < 2)
        bk = *(const bf16x8*)&QKb[(s0 + sbt * 16 + lm) * 384 + 192 + h * 16 + quad * 8];
      f32x4 z = {0.f, 0.f, 0.f, 0.f};
      qk[sbt] = __builtin_amdgcn_mfma_f32_16x16x32_bf16(aq, bk, z, 0, 0, 0);
    }
#pragma unroll
    for (int sbt = 0; sbt < 4; ++sbt) {
#pragma unroll
      for (int r = 0; r < 4; ++r) {
        const int tl = tbase + quad * 4 + r;       // global t
        const int sl = sbt * 16 + lm;              // s within tile
        float x = qk[sbt][r];
        float val = (s0 + sl <= tl) ? 1.f + 0.25f * x + 0.03125f * x * x : 0.f;
        dsum[r] += val;
        sw[(quad * 4 + r) * 72 + sl] = f2bf(val);
      }
    }
#pragma unroll
    for (int kb = 0; kb < 2; ++kb) {
      bf16x8 a = *(const bf16x8*)&sw[lm * 72 + kb * 32 + quad * 8];
#pragma unroll
      for (int dt = 0; dt < 4; ++dt) {
        bf16x8 b = *(const bf16x8*)&vbase[dt * 16 * 512 + s0 + kb * 32 + quad * 8];
        av[dt] = __builtin_amdgcn_mfma_f32_16x16x32_bf16(a, b, av[dt], 0, 0, 0);
      }
    }
  }
#pragma unroll
  for (int r = 0; r < 4; ++r) {
    float v = dsum[r];
    v += __shfl_xor(v, 1); v += __shfl_xor(v, 2);
    v += __shfl_xor(v, 4); v += __shfl_xor(v, 8);
    if (lm == 0) denb[w][quad * 4 + r] = v;
  }
#pragma unroll
  for (int dt = 0; dt < 4; ++dt) partAV[w][dt][lane] = av[dt];
  __syncthreads();
  {
    // wave w finalizes d-tile dt=w: y = num/den, bf16
    f32x4 s = partAV[0][w][lane] + partAV[1][w][lane] +
              partAV[2][w][lane] + partAV[3][w][lane];
#pragma unroll
    for (int r = 0; r < 4; ++r) {
      const int row = quad * 4 + r;
      float den = denb[0][row] + denb[1][row] + denb[2][row] + denb[3][row] + 1e-12f;
      Yb[(tbase + row) * 768 + h * 64 + w * 16 + lm] = f2bf(s[r] / den);
    }
  }
}

// ---- out GEMM: pure bf16 32x32 tile, split-K x4: out = Yb @ Wo^T ----
__global__ __launch_bounds__(256) void gemm_out(
    const unsigned short* __restrict__ Yb, const unsigned short* __restrict__ Wob,
    float* __restrict__ out) {
  __shared__ f32x4 part[4][4][64];
  const int tid = threadIdx.x;
  const int w = tid >> 6, lane = tid & 63;
  const int lm = lane & 15, quad = lane >> 4;
  const int mt = blockIdx.y * 32;
  const int n0 = blockIdx.x * 32;
  const int kw = w * 192;
  const unsigned short* a_ptr = Yb + (mt + lm) * 768 + kw + quad * 8;
  const unsigned short* b_ptr = Wob + (n0 + lm) * 768 + kw + quad * 8;
  f32x4 acc[4] = {{0.f,0.f,0.f,0.f},{0.f,0.f,0.f,0.f},{0.f,0.f,0.f,0.f},{0.f,0.f,0.f,0.f}};
#pragma unroll
  for (int kb = 0; kb < 192; kb += 32) {
    bf16x8 a0 = *(const bf16x8*)(a_ptr + kb);
    bf16x8 a1 = *(const bf16x8*)(a_ptr + 16 * 768 + kb);
    bf16x8 b0 = *(const bf16x8*)(b_ptr + kb);
    bf16x8 b1 = *(const bf16x8*)(b_ptr + 16 * 768 + kb);
    acc[0] = __builtin_amdgcn_mfma_f32_16x16x32_bf16(a0, b0, acc[0], 0, 0, 0);
    acc[1] = __builtin_amdgcn_mfma_f32_16x16x32_bf16(a0, b1, acc[1], 0, 0, 0);
    acc[2] = __builtin_amdgcn_mfma_f32_16x16x32_bf16(a1, b0, acc[2], 0, 0, 0);
    acc[3] = __builtin_amdgcn_mfma_f32_16x16x32_bf16(a1, b1, acc[3], 0, 0, 0);
  }
#pragma unroll
  for (int s = 0; s < 4; ++s) part[w][s][lane] = acc[s];
  __syncthreads();
  {
    const int m = mt + (w >> 1) * 16;
    const int n = n0 + (w & 1) * 16;
    f32x4 s = part[0][w][lane] + part[1][w][lane] + part[2][w][lane] + part[3][w][lane];
#pragma unroll
    for (int r = 0; r < 4; ++r)
      out[(m + quad * 4 + r) * 768 + n + lm] = s[r];
  }
}

extern "C" void kernel_launch(void* const* d_in, const int* in_sizes, int n_in,
                              void* d_out, int out_size, void* d_ws, size_t ws_size,
                              hipStream_t stream) {
  const float* hs = (const float*)d_in[0];
  const float* Wq = (const float*)d_in[1];
  const float* Wk = (const float*)d_in[2];
  const float* Wv = (const float*)d_in[3];
  const float* Wo = (const float*)d_in[4];
  float* out = (float*)d_out;
  float* ws = (float*)d_ws;

  unsigned short* Yb    = (unsigned short*)ws;             // 393216 us
  unsigned short* hsb   = Yb + 393216;                     // 393216 us
  unsigned short* Wqkvb = hsb + 393216;                    // 884736 us
  unsigned short* Wob   = Wqkvb + 884736;                  // 589824 us
  unsigned short* QKb   = Wob + 589824;                    // 196608 us
  unsigned short* Vt    = QKb + 196608;                    // 393216 us

  // casts (8 elems/thread, 16B stores)
  prep<<<dim3(912), 256, 0, stream>>>(hs, Wq, Wk, Wv, Wo, hsb, Wqkvb, Wob);
  // QKV projections; V emitted transposed (32x32 tiles)
  gemm_qkv<<<dim3(36, 16), 256, 0, stream>>>(hsb, Wqkvb, QKb, Vt);
  // causal taylor attention -> Yb = bf16(num/den)
  attn<<<dim3(8, 12, 4), 256, 0, stream>>>(QKb, Vt, Yb);
  // out = Yb @ Wo^T (pure bf16 GEMM)
  gemm_out<<<dim3(24, 16), 256, 0, stream>>>(Yb, Wob, out);
}